// Round 10
// baseline (121.818 us; speedup 1.0000x reference)
//
#include <hip/hip_runtime.h>

// ---------------------------------------------------------------------------
// SparseAttention v8.1: v7 (112.8us) minus the x-split prep round-trip.
// prep_w (weight transpose only) -> gemm_qkv_f (A staged fp32 via glds,
// hi/lo bf16 split in VGPR after ds_read) -> full-MFMA attention (bf16 out)
// -> single-product out GEMM.
// B=2 S=2048 D=512 H=8 hd=64, fp32 I/O.
// v8.1: split2 via manual RTNE bit ops (__hip_bfloat162 not bit_cast-able).
// Lessons held: no direct-fragment global loads (R6), no cooperative launch
// (R7), glds staging + XOR swizzle + 128-tile is the plateau structure.
// ---------------------------------------------------------------------------

typedef __bf16 bf16x8 __attribute__((ext_vector_type(8)));
typedef float  f32x4  __attribute__((ext_vector_type(4)));
typedef unsigned short u16;
typedef unsigned int   u32;

__device__ __forceinline__ u16 f2bf(float f) {
  u32 u = __builtin_bit_cast(u32, f);
  u += 0x7FFFu + ((u >> 16) & 1u);
  return (u16)(u >> 16);
}
__device__ __forceinline__ float bf2f(u16 u) {
  return __builtin_bit_cast(float, ((u32)u) << 16);
}
__device__ __forceinline__ u32 pack2(u16 a, u16 b) {
  return (u32)a | ((u32)b << 16);
}
__device__ __forceinline__ void glds16(const void* g, void* l) {
  __builtin_amdgcn_global_load_lds(
      (const __attribute__((address_space(1))) void*)g,
      (__attribute__((address_space(3))) void*)l, 16, 0, 0);
}
__device__ __forceinline__ f32x4 mfma16(bf16x8 a, bf16x8 b, f32x4 c) {
  return __builtin_amdgcn_mfma_f32_16x16x32_bf16(a, b, c, 0, 0, 0);
}
// split two fp32 into packed hi-bf16 pair + lo-bf16 pair (RTNE both)
__device__ __forceinline__ void split2(float a, float b, u32& hu, u32& lu) {
  u16 h0 = f2bf(a), h1 = f2bf(b);
  hu = pack2(h0, h1);
  lu = pack2(f2bf(a - bf2f(h0)), f2bf(b - bf2f(h1)));
}

// ---------------------------------------------------------------------------
// prep_w: weight transposes only. blocks [0,768): w_qkv -> wqt[n][k] bf16;
// [768,1024): w_out -> wot[n][k] bf16.
// ---------------------------------------------------------------------------
__global__ __launch_bounds__(256) void prep_w(
    const float* __restrict__ Wq, u16* __restrict__ Wqt,
    const float* __restrict__ Wo, u16* __restrict__ Wot) {
  __shared__ float T[32][33];
  const int blk = blockIdx.x, t = threadIdx.x;
  const float* W;
  u16* Wt;
  int n0, k0, N;
  if (blk < 768) {
    W = Wq; Wt = Wqt; N = 1536;
    n0 = (blk % 48) * 32; k0 = (blk / 48) * 32;
  } else {
    int idx = blk - 768;
    W = Wo; Wt = Wot; N = 512;
    n0 = (idx % 16) * 32; k0 = (idx / 16) * 32;
  }
  const int r = t >> 3, c = (t & 7) * 4;
  float4 v = *(const float4*)&W[(size_t)(k0 + r) * N + n0 + c];
  T[c][r] = v.x; T[c + 1][r] = v.y; T[c + 2][r] = v.z; T[c + 3][r] = v.w;
  __syncthreads();
  u16 a = f2bf(T[r][c]),      b = f2bf(T[r][c + 1]);
  u16 cc = f2bf(T[r][c + 2]), d = f2bf(T[r][c + 3]);
  *(uint2*)&Wt[(size_t)(n0 + r) * 512 + k0 + c] =
      make_uint2(pack2(a, b), pack2(cc, d));
}

// ---------------------------------------------------------------------------
// gemm_qkv_f: x fp32 [4096,512] @ wqt[1536][512]^T + bias -> Q*0.125/K/V bf16.
// 128x128 tile, BK=32. A staged as fp32 via glds (16KB/iter), split to hi/lo
// bf16 in VGPR after ds_read. B staged bf16 (8KB).
// A swizzle: 16B-chunk index XOR (row&7) (fp32 rows are 128B = 8 chunks).
// B swizzle: 16B-quad XOR ((row>>1)&3) (bf16 rows are 64B = 4 quads).
// ---------------------------------------------------------------------------
__global__ __launch_bounds__(256) void gemm_qkv_f(
    const float* __restrict__ X, const u16* __restrict__ Bt,
    const float* __restrict__ bias,
    u16* __restrict__ Qb, u16* __restrict__ Kb, u16* __restrict__ Vb) {
  __shared__ __align__(16) float sA[128 * 32];   // fp32 A tile, 16 KB
  __shared__ __align__(16) u16   sB[128 * 32];   // bf16 B tile,  8 KB

  const int t = threadIdx.x, l = t & 63, w = t >> 6;
  const int wm = w >> 1, wn = w & 1;
  const int mBase = blockIdx.y * 128, nBase = blockIdx.x * 128;

  // ---- A staging: wave w stages rows [w*32, w*32+32), 4 glds, 8 rows each.
  const int qA = l >> 3;                    // row within 8
  const int cA = (l & 7) ^ (qA & 7);        // swizzled 16B chunk (4 floats)
  const float* gA[4];
  float* lA[4];
#pragma unroll
  for (int i = 0; i < 4; ++i) {
    int row = w * 32 + i * 8 + qA;
    gA[i] = X + (size_t)(mBase + row) * 512 + cA * 4;
    lA[i] = sA + (w * 32 + i * 8) * 32;     // wave-uniform base
  }
  // ---- B staging: rows [w*32, w*32+32), 2 glds, 16 rows each.
  const int qB = l >> 2;                    // row within 16
  const int kqB = ((l & 3) ^ ((qB >> 1) & 3)) * 8;  // swizzled quad (shorts)
  const u16* gB0 = Bt + (size_t)(nBase + w * 32 + qB) * 512 + kqB;
  const u16* gB1 = Bt + (size_t)(nBase + w * 32 + 16 + qB) * 512 + kqB;
  u16* lB0 = sB + (w * 32) * 32;
  u16* lB1 = sB + (w * 32 + 16) * 32;

  // ---- fragment offsets ----
  const int r15 = l & 15, kg = l >> 4;
  const int swA = r15 & 7;                  // A chunk swizzle key
  int aoffs[4][2];                          // two b128 reads per A frag
#pragma unroll
  for (int mt = 0; mt < 4; ++mt) {
    int row = wm * 64 + mt * 16 + r15;
    aoffs[mt][0] = row * 32 + ((kg * 2) ^ swA) * 4;
    aoffs[mt][1] = row * 32 + ((kg * 2 + 1) ^ swA) * 4;
  }
  const int pqB = (kg ^ ((r15 >> 1) & 3)) * 8;
  int boff[4];
#pragma unroll
  for (int nt = 0; nt < 4; ++nt) boff[nt] = (wn * 64 + nt * 16 + r15) * 32 + pqB;

  f32x4 acc[4][4];
#pragma unroll
  for (int i = 0; i < 4; ++i)
#pragma unroll
    for (int j = 0; j < 4; ++j) acc[i][j] = (f32x4){0.f, 0.f, 0.f, 0.f};

  for (int k0 = 0; k0 < 512; k0 += 32) {
#pragma unroll
    for (int i = 0; i < 4; ++i) glds16(gA[i] + k0, lA[i]);
    glds16(gB0 + k0, lB0);
    glds16(gB1 + k0, lB1);
    __syncthreads();

    bf16x8 b[4];
#pragma unroll
    for (int nt = 0; nt < 4; ++nt) b[nt] = *(const bf16x8*)(sB + boff[nt]);
#pragma unroll
    for (int mt = 0; mt < 4; ++mt) {
      float4 f0 = *(const float4*)(sA + aoffs[mt][0]);  // k = kg*8 .. +4
      float4 f1 = *(const float4*)(sA + aoffs[mt][1]);  // k = kg*8+4 .. +8
      union { bf16x8 v; u32 u[4]; } ah, al;
      split2(f0.x, f0.y, ah.u[0], al.u[0]);
      split2(f0.z, f0.w, ah.u[1], al.u[1]);
      split2(f1.x, f1.y, ah.u[2], al.u[2]);
      split2(f1.z, f1.w, ah.u[3], al.u[3]);
#pragma unroll
      for (int nt = 0; nt < 4; ++nt) {
        acc[mt][nt] = mfma16(ah.v, b[nt], acc[mt][nt]);
        acc[mt][nt] = mfma16(al.v, b[nt], acc[mt][nt]);
      }
    }
    __syncthreads();
  }

  const int lq = l >> 4;
  const int seg = nBase >> 9, colb = nBase & 511;
#pragma unroll
  for (int mt = 0; mt < 4; ++mt) {
    int row0 = mBase + wm * 64 + mt * 16 + lq * 4;
#pragma unroll
    for (int nt = 0; nt < 4; ++nt) {
      int col = wn * 64 + nt * 16 + r15;
      float bv = bias[nBase + col];
      int cc = colb + col;
      if (seg == 0) {
#pragma unroll
        for (int r = 0; r < 4; ++r)
          Qb[(size_t)(row0 + r) * 512 + cc] = f2bf((acc[mt][nt][r] + bv) * 0.125f);
      } else if (seg == 1) {
#pragma unroll
        for (int r = 0; r < 4; ++r)
          Kb[(size_t)(row0 + r) * 512 + cc] = f2bf(acc[mt][nt][r] + bv);
      } else {
#pragma unroll
        for (int r = 0; r < 4; ++r)
          Vb[(size_t)(row0 + r) * 512 + cc] = f2bf(acc[mt][nt][r] + bv);
      }
    }
  }
}

// ---------------------------------------------------------------------------
// attn_mfma: per (64-row tile, h, b). QK^T and PV on matrix cores.
// Writes attention output as bf16 (single-product out-GEMM downstream).
// ---------------------------------------------------------------------------
__global__ __launch_bounds__(256) void attn_mfma(
    const u16* __restrict__ Qb, const u16* __restrict__ Kb,
    const u16* __restrict__ Vb, u16* __restrict__ Oh) {
  const int tile = blockIdx.x, h = blockIdx.y, b = blockIdx.z;
  const int base = tile * 64;
  const size_t hb = (size_t)b * 2048;

  __shared__ __align__(16) u16 Qs[64][72];    // [s][d]
  __shared__ __align__(16) u16 Ks[128][72];   // [j][d]
  __shared__ __align__(16) u16 Vt[64][136];   // [d][j]
  __shared__ __align__(16) u16 Pp[64][136];   // [s][j]

  const int t = threadIdx.x, l = t & 63, w = t >> 6;
  const int r15 = l & 15, kg = l >> 4;

  // stage Q
  {
    int r = t >> 2, c0 = (t & 3) * 16;
    const uint4* src = (const uint4*)&Qb[(hb + base + r) * 512 + h * 64 + c0];
    *(uint4*)&Qs[r][c0] = src[0];
    *(uint4*)&Qs[r][c0 + 8] = src[1];
  }
  // stage K (clamped band)
  {
    int j = t >> 1, half = (t & 1) * 32;
    int ja = min(max(base - 32 + j, 0), 2047);
    const uint4* src = (const uint4*)&Kb[(hb + ja) * 512 + h * 64 + half];
    uint4* dst = (uint4*)&Ks[j][half];
    dst[0] = src[0]; dst[1] = src[1]; dst[2] = src[2]; dst[3] = src[3];
  }
  // stage V transposed
  {
    int j = t >> 1, ds = (t & 1) * 32;
    int ja = min(max(base - 32 + j, 0), 2047);
    const u16* src = &Vb[(hb + ja) * 512 + h * 64 + ds];
    u16 tmp[32];
    *(uint4*)&tmp[0]  = *(const uint4*)(src);
    *(uint4*)&tmp[8]  = *(const uint4*)(src + 8);
    *(uint4*)&tmp[16] = *(const uint4*)(src + 16);
    *(uint4*)&tmp[24] = *(const uint4*)(src + 24);
#pragma unroll
    for (int i = 0; i < 32; ++i) Vt[ds + i][j] = tmp[i];
  }
  __syncthreads();

  // QK^T: wave w owns rows [w*16, w*16+16)
  bf16x8 aQ0 = *(const bf16x8*)&Qs[w * 16 + r15][kg * 8];
  bf16x8 aQ1 = *(const bf16x8*)&Qs[w * 16 + r15][32 + kg * 8];
  f32x4 zero = (f32x4){0.f, 0.f, 0.f, 0.f};
  f32x4 sacc[8];
#pragma unroll
  for (int nt = 0; nt < 8; ++nt) {
    bf16x8 b0 = *(const bf16x8*)&Ks[nt * 16 + r15][kg * 8];
    bf16x8 b1 = *(const bf16x8*)&Ks[nt * 16 + r15][32 + kg * 8];
    sacc[nt] = mfma16(aQ0, b0, zero);
    sacc[nt] = mfma16(aQ1, b1, sacc[nt]);
  }

  // mask + softmax (C-layout: row = w*16+kg*4+r, col = nt*16+r15)
#pragma unroll
  for (int r = 0; r < 4; ++r) {
    int s_abs = base + w * 16 + kg * 4 + r;
    float m = -3.0e38f;
#pragma unroll
    for (int nt = 0; nt < 8; ++nt) {
      int j_abs = base - 32 + nt * 16 + r15;
      int dlt = j_abs - s_abs;
      bool valid = (dlt >= -32) && (dlt <= 32) && (j_abs >= 0) && (j_abs < 2048);
      float v = valid ? sacc[nt][r] : -1.0e9f;
      sacc[nt][r] = v;
      m = fmaxf(m, v);
    }
#pragma unroll
    for (int msk = 1; msk < 16; msk <<= 1) m = fmaxf(m, __shfl_xor(m, msk, 64));
    float s_ = 0.f;
#pragma unroll
    for (int nt = 0; nt < 8; ++nt) {
      float e = __expf(sacc[nt][r] - m);
      sacc[nt][r] = e;
      s_ += e;
    }
#pragma unroll
    for (int msk = 1; msk < 16; msk <<= 1) s_ += __shfl_xor(s_, msk, 64);
    float inv = 1.0f / s_;
#pragma unroll
    for (int nt = 0; nt < 8; ++nt)
      Pp[w * 16 + kg * 4 + r][nt * 16 + r15] = f2bf(sacc[nt][r] * inv);
  }
  __syncthreads();

  // PV
  bf16x8 aP[4];
#pragma unroll
  for (int kt = 0; kt < 4; ++kt)
    aP[kt] = *(const bf16x8*)&Pp[w * 16 + r15][kt * 32 + kg * 8];
  f32x4 oacc[4];
#pragma unroll
  for (int nt = 0; nt < 4; ++nt) oacc[nt] = zero;
#pragma unroll
  for (int nt = 0; nt < 4; ++nt) {
#pragma unroll
    for (int kt = 0; kt < 4; ++kt) {
      bf16x8 bV = *(const bf16x8*)&Vt[nt * 16 + r15][kt * 32 + kg * 8];
      oacc[nt] = mfma16(aP[kt], bV, oacc[nt]);
    }
  }

  // epilogue: write O as bf16
#pragma unroll
  for (int nt = 0; nt < 4; ++nt) {
#pragma unroll
    for (int r = 0; r < 4; ++r) {
      size_t idx =
          (hb + base + w * 16 + kg * 4 + r) * 512 + h * 64 + nt * 16 + r15;
      Oh[idx] = f2bf(oacc[nt][r]);
    }
  }
}

// ---------------------------------------------------------------------------
// gemm_out: [4096,512](bf16) @ [512,512]^T(bf16) + bias -> fp32 out.
// Single-product. 64x128 tile, grid (4,64) = 256 blocks. LDS 12KB.
// ---------------------------------------------------------------------------
__global__ __launch_bounds__(256) void gemm_out(
    const u16* __restrict__ Ah, const u16* __restrict__ Bt,
    const float* __restrict__ bias, float* __restrict__ Cf) {
  __shared__ __align__(16) u16 sAh[64 * 32];
  __shared__ __align__(16) u16 sB[128 * 32];

  const int t = threadIdx.x, l = t & 63, w = t >> 6;
  const int wm = w >> 1, wn = w & 1;
  const int mBase = blockIdx.y * 64, nBase = blockIdx.x * 128;

  const int q = l >> 2;
  const int kq = ((l & 3) ^ ((q >> 1) & 3)) * 8;
  const int rA = w * 16 + q;
  const u16* gAh = Ah + (size_t)(mBase + rA) * 512 + kq;
  const u16* gB0 = Bt + (size_t)(nBase + rA) * 512 + kq;
  const u16* gB1 = Bt + (size_t)(nBase + 64 + rA) * 512 + kq;
  u16* lAh = sAh + w * 512;
  u16* lB0 = sB + w * 512;
  u16* lB1 = sB + (w + 4) * 512;

  const int r15 = l & 15, kg = l >> 4;
  const int pq = (kg ^ ((r15 >> 1) & 3)) * 8;
  const int aoff0 = (wm * 32 + r15) * 32 + pq;
  const int aoff1 = aoff0 + 16 * 32;
  int boff[4];
#pragma unroll
  for (int nt = 0; nt < 4; ++nt) boff[nt] = (wn * 64 + nt * 16 + r15) * 32 + pq;

  f32x4 acc[2][4];
#pragma unroll
  for (int i = 0; i < 2; ++i)
#pragma unroll
    for (int j = 0; j < 4; ++j) acc[i][j] = (f32x4){0.f, 0.f, 0.f, 0.f};

  for (int k0 = 0; k0 < 512; k0 += 32) {
    glds16(gAh + k0, lAh);
    glds16(gB0 + k0, lB0);
    glds16(gB1 + k0, lB1);
    __syncthreads();
    bf16x8 a0 = *(const bf16x8*)(sAh + aoff0);
    bf16x8 a1 = *(const bf16x8*)(sAh + aoff1);
#pragma unroll
    for (int nt = 0; nt < 4; ++nt) {
      bf16x8 bb = *(const bf16x8*)(sB + boff[nt]);
      acc[0][nt] = mfma16(a0, bb, acc[0][nt]);
      acc[1][nt] = mfma16(a1, bb, acc[1][nt]);
    }
    __syncthreads();
  }

  const int lq = l >> 4;
#pragma unroll
  for (int mt = 0; mt < 2; ++mt) {
    int row0 = mBase + wm * 32 + mt * 16 + lq * 4;
#pragma unroll
    for (int nt = 0; nt < 4; ++nt) {
      int col = nBase + wn * 64 + nt * 16 + r15;
      float bv = bias[col];
#pragma unroll
      for (int r = 0; r < 4; ++r)
        Cf[(size_t)(row0 + r) * 512 + col] = acc[mt][nt][r] + bv;
    }
  }
}

// ---------------------------------------------------------------------------
extern "C" void kernel_launch(void* const* d_in, const int* in_sizes, int n_in,
                              void* d_out, int out_size, void* d_ws, size_t ws_size,
                              hipStream_t stream) {
  const float* x     = (const float*)d_in[0];
  const float* w_qkv = (const float*)d_in[1];
  const float* b_qkv = (const float*)d_in[2];
  const float* w_out = (const float*)d_in[3];
  const float* b_out = (const float*)d_in[4];
  float* out = (float*)d_out;

  // workspace layout (~18.9 MB)
  char* ws = (char*)d_ws;
  u16* wqt = (u16*)(ws + 0);          // 1536x512 bf16 = 1572864
  u16* wot = (u16*)(ws + 1572864);    // 512x512 bf16  = 524288
  u16* qb  = (u16*)(ws + 2097152);    // 4096x512 bf16 (pre-scaled) = 4194304
  u16* kb  = (u16*)(ws + 6291456);    // 4194304
  u16* vb  = (u16*)(ws + 10485760);   // 4194304
  u16* aoh = (u16*)(ws + 14680064);   // 4194304

  prep_w<<<1024, 256, 0, stream>>>(w_qkv, wqt, w_out, wot);
  gemm_qkv_f<<<dim3(12, 32), 256, 0, stream>>>(x, wqt, b_qkv, qb, kb, vb);
  attn_mfma<<<dim3(32, 8, 2), 256, 0, stream>>>(qb, kb, vb, aoh);
  gemm_out<<<dim3(4, 64), 256, 0, stream>>>(aoh, wot, b_out, out);
}

// Round 11
// 105.539 us; speedup vs baseline: 1.1543x; 1.1543x over previous
//
#include <hip/hip_runtime.h>

// ---------------------------------------------------------------------------
// SparseAttention v9: v7 structure (known-good 112.8us) with single-product
// QKV GEMM (error budget: harness compares at bf16 granularity; absmax pinned
// at 1 ulp = 9.77e-4 through all precision reductions so far).
// prep (x->bf16, weight transposes) -> gemm_qkv (bf16 A/B, 16 MFMA/iter,
// 128x128 glds tile) -> full-MFMA attention (bf16 out) -> single-product
// out GEMM. B=2 S=2048 D=512 H=8 hd=64, fp32 I/O.
// Lessons held: no direct-fragment global loads (R6), no cooperative launch
// (R7), no in-loop fp32->bf16 split on the ds_read->MFMA chain (R10).
// ---------------------------------------------------------------------------

typedef __bf16 bf16x8 __attribute__((ext_vector_type(8)));
typedef float  f32x4  __attribute__((ext_vector_type(4)));
typedef unsigned short u16;
typedef unsigned int   u32;

__device__ __forceinline__ u16 f2bf(float f) {
  u32 u = __builtin_bit_cast(u32, f);
  u += 0x7FFFu + ((u >> 16) & 1u);
  return (u16)(u >> 16);
}
__device__ __forceinline__ u32 pack2(u16 a, u16 b) {
  return (u32)a | ((u32)b << 16);
}
__device__ __forceinline__ void glds16(const void* g, void* l) {
  __builtin_amdgcn_global_load_lds(
      (const __attribute__((address_space(1))) void*)g,
      (__attribute__((address_space(3))) void*)l, 16, 0, 0);
}
__device__ __forceinline__ f32x4 mfma16(bf16x8 a, bf16x8 b, f32x4 c) {
  return __builtin_amdgcn_mfma_f32_16x16x32_bf16(a, b, c, 0, 0, 0);
}

// ---------------------------------------------------------------------------
// prep: blocks [0,2048): round x to bf16 (float4/thread). [2048,2816):
// transpose+round w_qkv. [2816,3072): transpose+round w_out.
// ---------------------------------------------------------------------------
__global__ __launch_bounds__(256) void prep(
    const float4* __restrict__ X, uint2* __restrict__ XH,
    const float* __restrict__ Wq, u16* __restrict__ Wqt,
    const float* __restrict__ Wo, u16* __restrict__ Wot) {
  __shared__ float T[32][33];
  const int blk = blockIdx.x, t = threadIdx.x;
  if (blk < 2048) {
    int i = blk * 256 + t;
    float4 v = X[i];
    XH[i] = make_uint2(pack2(f2bf(v.x), f2bf(v.y)), pack2(f2bf(v.z), f2bf(v.w)));
    return;
  }
  const float* W;
  u16* Wt;
  int n0, k0, N;
  if (blk < 2816) {
    int idx = blk - 2048;
    W = Wq; Wt = Wqt; N = 1536;
    n0 = (idx % 48) * 32; k0 = (idx / 48) * 32;
  } else {
    int idx = blk - 2816;
    W = Wo; Wt = Wot; N = 512;
    n0 = (idx % 16) * 32; k0 = (idx / 16) * 32;
  }
  const int r = t >> 3, c = (t & 7) * 4;
  float4 v = *(const float4*)&W[(size_t)(k0 + r) * N + n0 + c];
  T[c][r] = v.x; T[c + 1][r] = v.y; T[c + 2][r] = v.z; T[c + 3][r] = v.w;
  __syncthreads();
  u16 a = f2bf(T[r][c]),      b = f2bf(T[r][c + 1]);
  u16 cc = f2bf(T[r][c + 2]), d = f2bf(T[r][c + 3]);
  *(uint2*)&Wt[(size_t)(n0 + r) * 512 + k0 + c] =
      make_uint2(pack2(a, b), pack2(cc, d));
}

// ---------------------------------------------------------------------------
// gemm_qkv: bf16(x) [4096,512] @ wqt[1536][512]^T + bias -> Q*0.125/K/V bf16.
// 128x128 tile, BK=32, single product, 16 MFMA/wave/iter, 16 KB LDS.
// ---------------------------------------------------------------------------
__global__ __launch_bounds__(256) void gemm_qkv(
    const u16* __restrict__ Ah, const u16* __restrict__ Bt,
    const float* __restrict__ bias,
    u16* __restrict__ Qb, u16* __restrict__ Kb, u16* __restrict__ Vb) {
  __shared__ __align__(16) u16 sAh[128 * 32];
  __shared__ __align__(16) u16 sB[128 * 32];

  const int t = threadIdx.x, l = t & 63, w = t >> 6;
  const int wm = w >> 1, wn = w & 1;
  const int mBase = blockIdx.y * 128, nBase = blockIdx.x * 128;

  const int q = l >> 2;
  const int kq = ((l & 3) ^ ((q >> 1) & 3)) * 8;
  const int rw0 = w * 32 + q, rw1 = rw0 + 16;
  const u16* gAh0 = Ah + (size_t)(mBase + rw0) * 512 + kq;
  const u16* gAh1 = Ah + (size_t)(mBase + rw1) * 512 + kq;
  const u16* gB0  = Bt + (size_t)(nBase + rw0) * 512 + kq;
  const u16* gB1  = Bt + (size_t)(nBase + rw1) * 512 + kq;
  u16* lAh0 = sAh + (w * 32) * 32;
  u16* lAh1 = sAh + (w * 32 + 16) * 32;
  u16* lB0  = sB + (w * 32) * 32;
  u16* lB1  = sB + (w * 32 + 16) * 32;

  const int r15 = l & 15, kg = l >> 4;
  const int pq = (kg ^ ((r15 >> 1) & 3)) * 8;
  int aoff[4], boff[4];
#pragma unroll
  for (int mt = 0; mt < 4; ++mt) aoff[mt] = (wm * 64 + mt * 16 + r15) * 32 + pq;
#pragma unroll
  for (int nt = 0; nt < 4; ++nt) boff[nt] = (wn * 64 + nt * 16 + r15) * 32 + pq;

  f32x4 acc[4][4];
#pragma unroll
  for (int i = 0; i < 4; ++i)
#pragma unroll
    for (int j = 0; j < 4; ++j) acc[i][j] = (f32x4){0.f, 0.f, 0.f, 0.f};

  for (int k0 = 0; k0 < 512; k0 += 32) {
    glds16(gAh0 + k0, lAh0);
    glds16(gAh1 + k0, lAh1);
    glds16(gB0 + k0, lB0);
    glds16(gB1 + k0, lB1);
    __syncthreads();
    bf16x8 b[4];
#pragma unroll
    for (int nt = 0; nt < 4; ++nt) b[nt] = *(const bf16x8*)(sB + boff[nt]);
#pragma unroll
    for (int mt = 0; mt < 4; ++mt) {
      bf16x8 ah = *(const bf16x8*)(sAh + aoff[mt]);
#pragma unroll
      for (int nt = 0; nt < 4; ++nt)
        acc[mt][nt] = mfma16(ah, b[nt], acc[mt][nt]);
    }
    __syncthreads();
  }

  const int lq = l >> 4;
  const int seg = nBase >> 9, colb = nBase & 511;
#pragma unroll
  for (int mt = 0; mt < 4; ++mt) {
    int row0 = mBase + wm * 64 + mt * 16 + lq * 4;
#pragma unroll
    for (int nt = 0; nt < 4; ++nt) {
      int col = wn * 64 + nt * 16 + r15;
      float bv = bias[nBase + col];
      int cc = colb + col;
      if (seg == 0) {
#pragma unroll
        for (int r = 0; r < 4; ++r)
          Qb[(size_t)(row0 + r) * 512 + cc] = f2bf((acc[mt][nt][r] + bv) * 0.125f);
      } else if (seg == 1) {
#pragma unroll
        for (int r = 0; r < 4; ++r)
          Kb[(size_t)(row0 + r) * 512 + cc] = f2bf(acc[mt][nt][r] + bv);
      } else {
#pragma unroll
        for (int r = 0; r < 4; ++r)
          Vb[(size_t)(row0 + r) * 512 + cc] = f2bf(acc[mt][nt][r] + bv);
      }
    }
  }
}

// ---------------------------------------------------------------------------
// attn_mfma: per (64-row tile, h, b). QK^T and PV on matrix cores.
// Writes attention output as bf16 (single-product out-GEMM downstream).
// ---------------------------------------------------------------------------
__global__ __launch_bounds__(256) void attn_mfma(
    const u16* __restrict__ Qb, const u16* __restrict__ Kb,
    const u16* __restrict__ Vb, u16* __restrict__ Oh) {
  const int tile = blockIdx.x, h = blockIdx.y, b = blockIdx.z;
  const int base = tile * 64;
  const size_t hb = (size_t)b * 2048;

  __shared__ __align__(16) u16 Qs[64][72];    // [s][d]
  __shared__ __align__(16) u16 Ks[128][72];   // [j][d]
  __shared__ __align__(16) u16 Vt[64][136];   // [d][j]
  __shared__ __align__(16) u16 Pp[64][136];   // [s][j]

  const int t = threadIdx.x, l = t & 63, w = t >> 6;
  const int r15 = l & 15, kg = l >> 4;

  // stage Q
  {
    int r = t >> 2, c0 = (t & 3) * 16;
    const uint4* src = (const uint4*)&Qb[(hb + base + r) * 512 + h * 64 + c0];
    *(uint4*)&Qs[r][c0] = src[0];
    *(uint4*)&Qs[r][c0 + 8] = src[1];
  }
  // stage K (clamped band)
  {
    int j = t >> 1, half = (t & 1) * 32;
    int ja = min(max(base - 32 + j, 0), 2047);
    const uint4* src = (const uint4*)&Kb[(hb + ja) * 512 + h * 64 + half];
    uint4* dst = (uint4*)&Ks[j][half];
    dst[0] = src[0]; dst[1] = src[1]; dst[2] = src[2]; dst[3] = src[3];
  }
  // stage V transposed
  {
    int j = t >> 1, ds = (t & 1) * 32;
    int ja = min(max(base - 32 + j, 0), 2047);
    const u16* src = &Vb[(hb + ja) * 512 + h * 64 + ds];
    u16 tmp[32];
    *(uint4*)&tmp[0]  = *(const uint4*)(src);
    *(uint4*)&tmp[8]  = *(const uint4*)(src + 8);
    *(uint4*)&tmp[16] = *(const uint4*)(src + 16);
    *(uint4*)&tmp[24] = *(const uint4*)(src + 24);
#pragma unroll
    for (int i = 0; i < 32; ++i) Vt[ds + i][j] = tmp[i];
  }
  __syncthreads();

  // QK^T: wave w owns rows [w*16, w*16+16)
  bf16x8 aQ0 = *(const bf16x8*)&Qs[w * 16 + r15][kg * 8];
  bf16x8 aQ1 = *(const bf16x8*)&Qs[w * 16 + r15][32 + kg * 8];
  f32x4 zero = (f32x4){0.f, 0.f, 0.f, 0.f};
  f32x4 sacc[8];
#pragma unroll
  for (int nt = 0; nt < 8; ++nt) {
    bf16x8 b0 = *(const bf16x8*)&Ks[nt * 16 + r15][kg * 8];
    bf16x8 b1 = *(const bf16x8*)&Ks[nt * 16 + r15][32 + kg * 8];
    sacc[nt] = mfma16(aQ0, b0, zero);
    sacc[nt] = mfma16(aQ1, b1, sacc[nt]);
  }

  // mask + softmax (C-layout: row = w*16+kg*4+r, col = nt*16+r15)
#pragma unroll
  for (int r = 0; r < 4; ++r) {
    int s_abs = base + w * 16 + kg * 4 + r;
    float m = -3.0e38f;
#pragma unroll
    for (int nt = 0; nt < 8; ++nt) {
      int j_abs = base - 32 + nt * 16 + r15;
      int dlt = j_abs - s_abs;
      bool valid = (dlt >= -32) && (dlt <= 32) && (j_abs >= 0) && (j_abs < 2048);
      float v = valid ? sacc[nt][r] : -1.0e9f;
      sacc[nt][r] = v;
      m = fmaxf(m, v);
    }
#pragma unroll
    for (int msk = 1; msk < 16; msk <<= 1) m = fmaxf(m, __shfl_xor(m, msk, 64));
    float s_ = 0.f;
#pragma unroll
    for (int nt = 0; nt < 8; ++nt) {
      float e = __expf(sacc[nt][r] - m);
      sacc[nt][r] = e;
      s_ += e;
    }
#pragma unroll
    for (int msk = 1; msk < 16; msk <<= 1) s_ += __shfl_xor(s_, msk, 64);
    float inv = 1.0f / s_;
#pragma unroll
    for (int nt = 0; nt < 8; ++nt)
      Pp[w * 16 + kg * 4 + r][nt * 16 + r15] = f2bf(sacc[nt][r] * inv);
  }
  __syncthreads();

  // PV
  bf16x8 aP[4];
#pragma unroll
  for (int kt = 0; kt < 4; ++kt)
    aP[kt] = *(const bf16x8*)&Pp[w * 16 + r15][kt * 32 + kg * 8];
  f32x4 oacc[4];
#pragma unroll
  for (int nt = 0; nt < 4; ++nt) oacc[nt] = zero;
#pragma unroll
  for (int nt = 0; nt < 4; ++nt) {
#pragma unroll
    for (int kt = 0; kt < 4; ++kt) {
      bf16x8 bV = *(const bf16x8*)&Vt[nt * 16 + r15][kt * 32 + kg * 8];
      oacc[nt] = mfma16(aP[kt], bV, oacc[nt]);
    }
  }

  // epilogue: write O as bf16
#pragma unroll
  for (int nt = 0; nt < 4; ++nt) {
#pragma unroll
    for (int r = 0; r < 4; ++r) {
      size_t idx =
          (hb + base + w * 16 + kg * 4 + r) * 512 + h * 64 + nt * 16 + r15;
      Oh[idx] = f2bf(oacc[nt][r]);
    }
  }
}

// ---------------------------------------------------------------------------
// gemm_out: [4096,512](bf16) @ [512,512]^T(bf16) + bias -> fp32 out.
// Single-product. 64x128 tile, grid (4,64) = 256 blocks. LDS 12KB.
// ---------------------------------------------------------------------------
__global__ __launch_bounds__(256) void gemm_out(
    const u16* __restrict__ Ah, const u16* __restrict__ Bt,
    const float* __restrict__ bias, float* __restrict__ Cf) {
  __shared__ __align__(16) u16 sAh[64 * 32];
  __shared__ __align__(16) u16 sB[128 * 32];

  const int t = threadIdx.x, l = t & 63, w = t >> 6;
  const int wm = w >> 1, wn = w & 1;
  const int mBase = blockIdx.y * 64, nBase = blockIdx.x * 128;

  const int q = l >> 2;
  const int kq = ((l & 3) ^ ((q >> 1) & 3)) * 8;
  const int rA = w * 16 + q;
  const u16* gAh = Ah + (size_t)(mBase + rA) * 512 + kq;
  const u16* gB0 = Bt + (size_t)(nBase + rA) * 512 + kq;
  const u16* gB1 = Bt + (size_t)(nBase + 64 + rA) * 512 + kq;
  u16* lAh = sAh + w * 512;
  u16* lB0 = sB + w * 512;
  u16* lB1 = sB + (w + 4) * 512;

  const int r15 = l & 15, kg = l >> 4;
  const int pq = (kg ^ ((r15 >> 1) & 3)) * 8;
  const int aoff0 = (wm * 32 + r15) * 32 + pq;
  const int aoff1 = aoff0 + 16 * 32;
  int boff[4];
#pragma unroll
  for (int nt = 0; nt < 4; ++nt) boff[nt] = (wn * 64 + nt * 16 + r15) * 32 + pq;

  f32x4 acc[2][4];
#pragma unroll
  for (int i = 0; i < 2; ++i)
#pragma unroll
    for (int j = 0; j < 4; ++j) acc[i][j] = (f32x4){0.f, 0.f, 0.f, 0.f};

  for (int k0 = 0; k0 < 512; k0 += 32) {
    glds16(gAh + k0, lAh);
    glds16(gB0 + k0, lB0);
    glds16(gB1 + k0, lB1);
    __syncthreads();
    bf16x8 a0 = *(const bf16x8*)(sAh + aoff0);
    bf16x8 a1 = *(const bf16x8*)(sAh + aoff1);
#pragma unroll
    for (int nt = 0; nt < 4; ++nt) {
      bf16x8 bb = *(const bf16x8*)(sB + boff[nt]);
      acc[0][nt] = mfma16(a0, bb, acc[0][nt]);
      acc[1][nt] = mfma16(a1, bb, acc[1][nt]);
    }
    __syncthreads();
  }

  const int lq = l >> 4;
#pragma unroll
  for (int mt = 0; mt < 2; ++mt) {
    int row0 = mBase + wm * 32 + mt * 16 + lq * 4;
#pragma unroll
    for (int nt = 0; nt < 4; ++nt) {
      int col = nBase + wn * 64 + nt * 16 + r15;
      float bv = bias[col];
#pragma unroll
      for (int r = 0; r < 4; ++r)
        Cf[(size_t)(row0 + r) * 512 + col] = acc[mt][nt][r] + bv;
    }
  }
}

// ---------------------------------------------------------------------------
extern "C" void kernel_launch(void* const* d_in, const int* in_sizes, int n_in,
                              void* d_out, int out_size, void* d_ws, size_t ws_size,
                              hipStream_t stream) {
  const float* x     = (const float*)d_in[0];
  const float* w_qkv = (const float*)d_in[1];
  const float* b_qkv = (const float*)d_in[2];
  const float* w_out = (const float*)d_in[3];
  const float* b_out = (const float*)d_in[4];
  float* out = (float*)d_out;

  // workspace layout (~22.6 MB)
  char* ws = (char*)d_ws;
  u16* xh  = (u16*)(ws + 0);          // 4096x512 bf16 = 4194304
  u16* wqt = (u16*)(ws + 4194304);    // 1536x512 bf16 = 1572864
  u16* wot = (u16*)(ws + 5767168);    // 512x512 bf16  = 524288
  u16* qb  = (u16*)(ws + 6291456);    // 4096x512 bf16 (pre-scaled) = 4194304
  u16* kb  = (u16*)(ws + 10485760);   // 4194304
  u16* vb  = (u16*)(ws + 14680064);   // 4194304
  u16* aoh = (u16*)(ws + 18874368);   // 4194304

  prep<<<3072, 256, 0, stream>>>((const float4*)x, (uint2*)xh,
                                 w_qkv, wqt, w_out, wot);
  gemm_qkv<<<dim3(12, 32), 256, 0, stream>>>(xh, wqt, b_qkv, qb, kb, vb);
  attn_mfma<<<dim3(32, 8, 2), 256, 0, stream>>>(qb, kb, vb, aoh);
  gemm_out<<<dim3(4, 64), 256, 0, stream>>>(aoh, wot, b_out, out);
}

// Round 12
// 103.277 us; speedup vs baseline: 1.1795x; 1.0219x over previous
//
#include <hip/hip_runtime.h>

// ---------------------------------------------------------------------------
// SparseAttention v10: v9 (105.5us) with gemm_qkv reshaped 128x128 -> 64x128
// tiles (768 blocks = 3/CU) to overlap the per-K-step barrier drains.
// prep (x->bf16, weight transposes) -> gemm_qkv (bf16 single-product, 64x128
// glds tile) -> full-MFMA attention (bf16 out) -> single-product out GEMM.
// B=2 S=2048 D=512 H=8 hd=64, fp32 I/O.
// Fixed-overhead model: dur = ~83us harness (256MiB ws poison + restores +
// graph) + kernel sum (~22us at v9). gemm_qkv/gemm_out are barrier-drain
// bound; overlap scales with blocks/CU (m114) -> more, smaller blocks.
// Lessons held: no direct-fragment global loads (R6), no cooperative launch
// (R7), no in-loop fp32->bf16 on the ds_read->MFMA chain (R10).
// ---------------------------------------------------------------------------

typedef __bf16 bf16x8 __attribute__((ext_vector_type(8)));
typedef float  f32x4  __attribute__((ext_vector_type(4)));
typedef unsigned short u16;
typedef unsigned int   u32;

__device__ __forceinline__ u16 f2bf(float f) {
  u32 u = __builtin_bit_cast(u32, f);
  u += 0x7FFFu + ((u >> 16) & 1u);
  return (u16)(u >> 16);
}
__device__ __forceinline__ u32 pack2(u16 a, u16 b) {
  return (u32)a | ((u32)b << 16);
}
__device__ __forceinline__ void glds16(const void* g, void* l) {
  __builtin_amdgcn_global_load_lds(
      (const __attribute__((address_space(1))) void*)g,
      (__attribute__((address_space(3))) void*)l, 16, 0, 0);
}
__device__ __forceinline__ f32x4 mfma16(bf16x8 a, bf16x8 b, f32x4 c) {
  return __builtin_amdgcn_mfma_f32_16x16x32_bf16(a, b, c, 0, 0, 0);
}

// ---------------------------------------------------------------------------
// prep: blocks [0,2048): round x to bf16 (float4/thread). [2048,2816):
// transpose+round w_qkv. [2816,3072): transpose+round w_out.
// ---------------------------------------------------------------------------
__global__ __launch_bounds__(256) void prep(
    const float4* __restrict__ X, uint2* __restrict__ XH,
    const float* __restrict__ Wq, u16* __restrict__ Wqt,
    const float* __restrict__ Wo, u16* __restrict__ Wot) {
  __shared__ float T[32][33];
  const int blk = blockIdx.x, t = threadIdx.x;
  if (blk < 2048) {
    int i = blk * 256 + t;
    float4 v = X[i];
    XH[i] = make_uint2(pack2(f2bf(v.x), f2bf(v.y)), pack2(f2bf(v.z), f2bf(v.w)));
    return;
  }
  const float* W;
  u16* Wt;
  int n0, k0, N;
  if (blk < 2816) {
    int idx = blk - 2048;
    W = Wq; Wt = Wqt; N = 1536;
    n0 = (idx % 48) * 32; k0 = (idx / 48) * 32;
  } else {
    int idx = blk - 2816;
    W = Wo; Wt = Wot; N = 512;
    n0 = (idx % 16) * 32; k0 = (idx / 16) * 32;
  }
  const int r = t >> 3, c = (t & 7) * 4;
  float4 v = *(const float4*)&W[(size_t)(k0 + r) * N + n0 + c];
  T[c][r] = v.x; T[c + 1][r] = v.y; T[c + 2][r] = v.z; T[c + 3][r] = v.w;
  __syncthreads();
  u16 a = f2bf(T[r][c]),      b = f2bf(T[r][c + 1]);
  u16 cc = f2bf(T[r][c + 2]), d = f2bf(T[r][c + 3]);
  *(uint2*)&Wt[(size_t)(n0 + r) * 512 + k0 + c] =
      make_uint2(pack2(a, b), pack2(cc, d));
}

// ---------------------------------------------------------------------------
// gemm_qkv: bf16(x) [4096,512] @ wqt[1536][512]^T + bias -> Q*0.125/K/V bf16.
// 64x128 tile, BK=32, single product. 4 waves (2x2), wave 32x64 = 2x4 mfma,
// 8 MFMA/wave/iter, 12 KB LDS. grid (12,64) = 768 blocks = 3/CU.
// ---------------------------------------------------------------------------
__global__ __launch_bounds__(256) void gemm_qkv(
    const u16* __restrict__ Ah, const u16* __restrict__ Bt,
    const float* __restrict__ bias,
    u16* __restrict__ Qb, u16* __restrict__ Kb, u16* __restrict__ Vb) {
  __shared__ __align__(16) u16 sAh[64 * 32];
  __shared__ __align__(16) u16 sB[128 * 32];

  const int t = threadIdx.x, l = t & 63, w = t >> 6;
  const int wm = w >> 1, wn = w & 1;
  const int mBase = blockIdx.y * 64, nBase = blockIdx.x * 128;

  const int q = l >> 2;
  const int kq = ((l & 3) ^ ((q >> 1) & 3)) * 8;
  const int rA = w * 16 + q;
  const u16* gAh = Ah + (size_t)(mBase + rA) * 512 + kq;
  const u16* gB0 = Bt + (size_t)(nBase + rA) * 512 + kq;
  const u16* gB1 = Bt + (size_t)(nBase + 64 + rA) * 512 + kq;
  u16* lAh = sAh + w * 512;
  u16* lB0 = sB + w * 512;
  u16* lB1 = sB + (w + 4) * 512;

  const int r15 = l & 15, kg = l >> 4;
  const int pq = (kg ^ ((r15 >> 1) & 3)) * 8;
  const int aoff0 = (wm * 32 + r15) * 32 + pq;
  const int aoff1 = aoff0 + 16 * 32;
  int boff[4];
#pragma unroll
  for (int nt = 0; nt < 4; ++nt) boff[nt] = (wn * 64 + nt * 16 + r15) * 32 + pq;

  f32x4 acc[2][4];
#pragma unroll
  for (int i = 0; i < 2; ++i)
#pragma unroll
    for (int j = 0; j < 4; ++j) acc[i][j] = (f32x4){0.f, 0.f, 0.f, 0.f};

  for (int k0 = 0; k0 < 512; k0 += 32) {
    glds16(gAh + k0, lAh);
    glds16(gB0 + k0, lB0);
    glds16(gB1 + k0, lB1);
    __syncthreads();
    bf16x8 a0 = *(const bf16x8*)(sAh + aoff0);
    bf16x8 a1 = *(const bf16x8*)(sAh + aoff1);
#pragma unroll
    for (int nt = 0; nt < 4; ++nt) {
      bf16x8 bb = *(const bf16x8*)(sB + boff[nt]);
      acc[0][nt] = mfma16(a0, bb, acc[0][nt]);
      acc[1][nt] = mfma16(a1, bb, acc[1][nt]);
    }
    __syncthreads();
  }

  const int lq = l >> 4;
  const int seg = nBase >> 9, colb = nBase & 511;
#pragma unroll
  for (int mt = 0; mt < 2; ++mt) {
    int row0 = mBase + wm * 32 + mt * 16 + lq * 4;
#pragma unroll
    for (int nt = 0; nt < 4; ++nt) {
      int col = wn * 64 + nt * 16 + r15;
      float bv = bias[nBase + col];
      int cc = colb + col;
      if (seg == 0) {
#pragma unroll
        for (int r = 0; r < 4; ++r)
          Qb[(size_t)(row0 + r) * 512 + cc] = f2bf((acc[mt][nt][r] + bv) * 0.125f);
      } else if (seg == 1) {
#pragma unroll
        for (int r = 0; r < 4; ++r)
          Kb[(size_t)(row0 + r) * 512 + cc] = f2bf(acc[mt][nt][r] + bv);
      } else {
#pragma unroll
        for (int r = 0; r < 4; ++r)
          Vb[(size_t)(row0 + r) * 512 + cc] = f2bf(acc[mt][nt][r] + bv);
      }
    }
  }
}

// ---------------------------------------------------------------------------
// attn_mfma: per (64-row tile, h, b). QK^T and PV on matrix cores.
// Writes attention output as bf16 (single-product out-GEMM downstream).
// ---------------------------------------------------------------------------
__global__ __launch_bounds__(256) void attn_mfma(
    const u16* __restrict__ Qb, const u16* __restrict__ Kb,
    const u16* __restrict__ Vb, u16* __restrict__ Oh) {
  const int tile = blockIdx.x, h = blockIdx.y, b = blockIdx.z;
  const int base = tile * 64;
  const size_t hb = (size_t)b * 2048;

  __shared__ __align__(16) u16 Qs[64][72];    // [s][d]
  __shared__ __align__(16) u16 Ks[128][72];   // [j][d]
  __shared__ __align__(16) u16 Vt[64][136];   // [d][j]
  __shared__ __align__(16) u16 Pp[64][136];   // [s][j]

  const int t = threadIdx.x, l = t & 63, w = t >> 6;
  const int r15 = l & 15, kg = l >> 4;

  // stage Q
  {
    int r = t >> 2, c0 = (t & 3) * 16;
    const uint4* src = (const uint4*)&Qb[(hb + base + r) * 512 + h * 64 + c0];
    *(uint4*)&Qs[r][c0] = src[0];
    *(uint4*)&Qs[r][c0 + 8] = src[1];
  }
  // stage K (clamped band)
  {
    int j = t >> 1, half = (t & 1) * 32;
    int ja = min(max(base - 32 + j, 0), 2047);
    const uint4* src = (const uint4*)&Kb[(hb + ja) * 512 + h * 64 + half];
    uint4* dst = (uint4*)&Ks[j][half];
    dst[0] = src[0]; dst[1] = src[1]; dst[2] = src[2]; dst[3] = src[3];
  }
  // stage V transposed
  {
    int j = t >> 1, ds = (t & 1) * 32;
    int ja = min(max(base - 32 + j, 0), 2047);
    const u16* src = &Vb[(hb + ja) * 512 + h * 64 + ds];
    u16 tmp[32];
    *(uint4*)&tmp[0]  = *(const uint4*)(src);
    *(uint4*)&tmp[8]  = *(const uint4*)(src + 8);
    *(uint4*)&tmp[16] = *(const uint4*)(src + 16);
    *(uint4*)&tmp[24] = *(const uint4*)(src + 24);
#pragma unroll
    for (int i = 0; i < 32; ++i) Vt[ds + i][j] = tmp[i];
  }
  __syncthreads();

  // QK^T: wave w owns rows [w*16, w*16+16)
  bf16x8 aQ0 = *(const bf16x8*)&Qs[w * 16 + r15][kg * 8];
  bf16x8 aQ1 = *(const bf16x8*)&Qs[w * 16 + r15][32 + kg * 8];
  f32x4 zero = (f32x4){0.f, 0.f, 0.f, 0.f};
  f32x4 sacc[8];
#pragma unroll
  for (int nt = 0; nt < 8; ++nt) {
    bf16x8 b0 = *(const bf16x8*)&Ks[nt * 16 + r15][kg * 8];
    bf16x8 b1 = *(const bf16x8*)&Ks[nt * 16 + r15][32 + kg * 8];
    sacc[nt] = mfma16(aQ0, b0, zero);
    sacc[nt] = mfma16(aQ1, b1, sacc[nt]);
  }

  // mask + softmax (C-layout: row = w*16+kg*4+r, col = nt*16+r15)
#pragma unroll
  for (int r = 0; r < 4; ++r) {
    int s_abs = base + w * 16 + kg * 4 + r;
    float m = -3.0e38f;
#pragma unroll
    for (int nt = 0; nt < 8; ++nt) {
      int j_abs = base - 32 + nt * 16 + r15;
      int dlt = j_abs - s_abs;
      bool valid = (dlt >= -32) && (dlt <= 32) && (j_abs >= 0) && (j_abs < 2048);
      float v = valid ? sacc[nt][r] : -1.0e9f;
      sacc[nt][r] = v;
      m = fmaxf(m, v);
    }
#pragma unroll
    for (int msk = 1; msk < 16; msk <<= 1) m = fmaxf(m, __shfl_xor(m, msk, 64));
    float s_ = 0.f;
#pragma unroll
    for (int nt = 0; nt < 8; ++nt) {
      float e = __expf(sacc[nt][r] - m);
      sacc[nt][r] = e;
      s_ += e;
    }
#pragma unroll
    for (int msk = 1; msk < 16; msk <<= 1) s_ += __shfl_xor(s_, msk, 64);
    float inv = 1.0f / s_;
#pragma unroll
    for (int nt = 0; nt < 8; ++nt)
      Pp[w * 16 + kg * 4 + r][nt * 16 + r15] = f2bf(sacc[nt][r] * inv);
  }
  __syncthreads();

  // PV
  bf16x8 aP[4];
#pragma unroll
  for (int kt = 0; kt < 4; ++kt)
    aP[kt] = *(const bf16x8*)&Pp[w * 16 + r15][kt * 32 + kg * 8];
  f32x4 oacc[4];
#pragma unroll
  for (int nt = 0; nt < 4; ++nt) oacc[nt] = zero;
#pragma unroll
  for (int nt = 0; nt < 4; ++nt) {
#pragma unroll
    for (int kt = 0; kt < 4; ++kt) {
      bf16x8 bV = *(const bf16x8*)&Vt[nt * 16 + r15][kt * 32 + kg * 8];
      oacc[nt] = mfma16(aP[kt], bV, oacc[nt]);
    }
  }

  // epilogue: write O as bf16
#pragma unroll
  for (int nt = 0; nt < 4; ++nt) {
#pragma unroll
    for (int r = 0; r < 4; ++r) {
      size_t idx =
          (hb + base + w * 16 + kg * 4 + r) * 512 + h * 64 + nt * 16 + r15;
      Oh[idx] = f2bf(oacc[nt][r]);
    }
  }
}

// ---------------------------------------------------------------------------
// gemm_out: [4096,512](bf16) @ [512,512]^T(bf16) + bias -> fp32 out.
// Single-product. 64x128 tile, grid (4,64) = 256 blocks. LDS 12KB.
// ---------------------------------------------------------------------------
__global__ __launch_bounds__(256) void gemm_out(
    const u16* __restrict__ Ah, const u16* __restrict__ Bt,
    const float* __restrict__ bias, float* __restrict__ Cf) {
  __shared__ __align__(16) u16 sAh[64 * 32];
  __shared__ __align__(16) u16 sB[128 * 32];

  const int t = threadIdx.x, l = t & 63, w = t >> 6;
  const int wm = w >> 1, wn = w & 1;
  const int mBase = blockIdx.y * 64, nBase = blockIdx.x * 128;

  const int q = l >> 2;
  const int kq = ((l & 3) ^ ((q >> 1) & 3)) * 8;
  const int rA = w * 16 + q;
  const u16* gAh = Ah + (size_t)(mBase + rA) * 512 + kq;
  const u16* gB0 = Bt + (size_t)(nBase + rA) * 512 + kq;
  const u16* gB1 = Bt + (size_t)(nBase + 64 + rA) * 512 + kq;
  u16* lAh = sAh + w * 512;
  u16* lB0 = sB + w * 512;
  u16* lB1 = sB + (w + 4) * 512;

  const int r15 = l & 15, kg = l >> 4;
  const int pq = (kg ^ ((r15 >> 1) & 3)) * 8;
  const int aoff0 = (wm * 32 + r15) * 32 + pq;
  const int aoff1 = aoff0 + 16 * 32;
  int boff[4];
#pragma unroll
  for (int nt = 0; nt < 4; ++nt) boff[nt] = (wn * 64 + nt * 16 + r15) * 32 + pq;

  f32x4 acc[2][4];
#pragma unroll
  for (int i = 0; i < 2; ++i)
#pragma unroll
    for (int j = 0; j < 4; ++j) acc[i][j] = (f32x4){0.f, 0.f, 0.f, 0.f};

  for (int k0 = 0; k0 < 512; k0 += 32) {
    glds16(gAh + k0, lAh);
    glds16(gB0 + k0, lB0);
    glds16(gB1 + k0, lB1);
    __syncthreads();
    bf16x8 a0 = *(const bf16x8*)(sAh + aoff0);
    bf16x8 a1 = *(const bf16x8*)(sAh + aoff1);
#pragma unroll
    for (int nt = 0; nt < 4; ++nt) {
      bf16x8 bb = *(const bf16x8*)(sB + boff[nt]);
      acc[0][nt] = mfma16(a0, bb, acc[0][nt]);
      acc[1][nt] = mfma16(a1, bb, acc[1][nt]);
    }
    __syncthreads();
  }

  const int lq = l >> 4;
#pragma unroll
  for (int mt = 0; mt < 2; ++mt) {
    int row0 = mBase + wm * 32 + mt * 16 + lq * 4;
#pragma unroll
    for (int nt = 0; nt < 4; ++nt) {
      int col = nBase + wn * 64 + nt * 16 + r15;
      float bv = bias[col];
#pragma unroll
      for (int r = 0; r < 4; ++r)
        Cf[(size_t)(row0 + r) * 512 + col] = acc[mt][nt][r] + bv;
    }
  }
}

// ---------------------------------------------------------------------------
extern "C" void kernel_launch(void* const* d_in, const int* in_sizes, int n_in,
                              void* d_out, int out_size, void* d_ws, size_t ws_size,
                              hipStream_t stream) {
  const float* x     = (const float*)d_in[0];
  const float* w_qkv = (const float*)d_in[1];
  const float* b_qkv = (const float*)d_in[2];
  const float* w_out = (const float*)d_in[3];
  const float* b_out = (const float*)d_in[4];
  float* out = (float*)d_out;

  // workspace layout (~22.6 MB)
  char* ws = (char*)d_ws;
  u16* xh  = (u16*)(ws + 0);          // 4096x512 bf16 = 4194304
  u16* wqt = (u16*)(ws + 4194304);    // 1536x512 bf16 = 1572864
  u16* wot = (u16*)(ws + 5767168);    // 512x512 bf16  = 524288
  u16* qb  = (u16*)(ws + 6291456);    // 4096x512 bf16 (pre-scaled) = 4194304
  u16* kb  = (u16*)(ws + 10485760);   // 4194304
  u16* vb  = (u16*)(ws + 14680064);   // 4194304
  u16* aoh = (u16*)(ws + 18874368);   // 4194304

  prep<<<3072, 256, 0, stream>>>((const float4*)x, (uint2*)xh,
                                 w_qkv, wqt, w_out, wot);
  gemm_qkv<<<dim3(12, 64), 256, 0, stream>>>(xh, wqt, b_qkv, qb, kb, vb);
  attn_mfma<<<dim3(32, 8, 2), 256, 0, stream>>>(qb, kb, vb, aoh);
  gemm_out<<<dim3(4, 64), 256, 0, stream>>>(aoh, wot, b_out, out);
}

// Round 13
// 100.449 us; speedup vs baseline: 1.2127x; 1.0282x over previous
//
#include <hip/hip_runtime.h>

// ---------------------------------------------------------------------------
// SparseAttention v11: v10 (103.3us) with BK=32 -> BK=64 in both GEMMs to
// halve the per-K-step barrier-drain count (16 -> 8 iters).
// prep (x->bf16, weight transposes) -> gemm_qkv (bf16 single-product, 64x128
// tile, BK=64, 24KB LDS, 768 blocks = 3/CU) -> full-MFMA attention ->
// single-product out GEMM (64x128, BK=64, 256 blocks).
// B=2 S=2048 D=512 H=8 hd=64, fp32 I/O.
// Swizzle for 128-B rows (64 shorts): 16B-quad' = quad ^ (row&7) -> 2-way
// bank aliasing (free, m136). Fixed-overhead model: ~83us harness + kernels.
// Lessons held: no direct-fragment global loads (R6), no cooperative launch
// (R7), no in-loop fp32->bf16 on the ds_read->MFMA chain (R10).
// ---------------------------------------------------------------------------

typedef __bf16 bf16x8 __attribute__((ext_vector_type(8)));
typedef float  f32x4  __attribute__((ext_vector_type(4)));
typedef unsigned short u16;
typedef unsigned int   u32;

__device__ __forceinline__ u16 f2bf(float f) {
  u32 u = __builtin_bit_cast(u32, f);
  u += 0x7FFFu + ((u >> 16) & 1u);
  return (u16)(u >> 16);
}
__device__ __forceinline__ u32 pack2(u16 a, u16 b) {
  return (u32)a | ((u32)b << 16);
}
__device__ __forceinline__ void glds16(const void* g, void* l) {
  __builtin_amdgcn_global_load_lds(
      (const __attribute__((address_space(1))) void*)g,
      (__attribute__((address_space(3))) void*)l, 16, 0, 0);
}
__device__ __forceinline__ f32x4 mfma16(bf16x8 a, bf16x8 b, f32x4 c) {
  return __builtin_amdgcn_mfma_f32_16x16x32_bf16(a, b, c, 0, 0, 0);
}

// ---------------------------------------------------------------------------
// prep: blocks [0,2048): round x to bf16 (float4/thread). [2048,2816):
// transpose+round w_qkv. [2816,3072): transpose+round w_out.
// ---------------------------------------------------------------------------
__global__ __launch_bounds__(256) void prep(
    const float4* __restrict__ X, uint2* __restrict__ XH,
    const float* __restrict__ Wq, u16* __restrict__ Wqt,
    const float* __restrict__ Wo, u16* __restrict__ Wot) {
  __shared__ float T[32][33];
  const int blk = blockIdx.x, t = threadIdx.x;
  if (blk < 2048) {
    int i = blk * 256 + t;
    float4 v = X[i];
    XH[i] = make_uint2(pack2(f2bf(v.x), f2bf(v.y)), pack2(f2bf(v.z), f2bf(v.w)));
    return;
  }
  const float* W;
  u16* Wt;
  int n0, k0, N;
  if (blk < 2816) {
    int idx = blk - 2048;
    W = Wq; Wt = Wqt; N = 1536;
    n0 = (idx % 48) * 32; k0 = (idx / 48) * 32;
  } else {
    int idx = blk - 2816;
    W = Wo; Wt = Wot; N = 512;
    n0 = (idx % 16) * 32; k0 = (idx / 16) * 32;
  }
  const int r = t >> 3, c = (t & 7) * 4;
  float4 v = *(const float4*)&W[(size_t)(k0 + r) * N + n0 + c];
  T[c][r] = v.x; T[c + 1][r] = v.y; T[c + 2][r] = v.z; T[c + 3][r] = v.w;
  __syncthreads();
  u16 a = f2bf(T[r][c]),      b = f2bf(T[r][c + 1]);
  u16 cc = f2bf(T[r][c + 2]), d = f2bf(T[r][c + 3]);
  *(uint2*)&Wt[(size_t)(n0 + r) * 512 + k0 + c] =
      make_uint2(pack2(a, b), pack2(cc, d));
}

// ---------------------------------------------------------------------------
// gemm_qkv: bf16(x) [4096,512] @ wqt[1536][512]^T + bias -> Q*0.125/K/V bf16.
// 64x128 tile, BK=64 (8 iters), single product. 4 waves 2x2, wave 32x64,
// 16 MFMA/wave/iter, 24 KB LDS. grid (12,64) = 768 blocks = 3/CU.
// LDS rows are 64 shorts (128 B); swizzle: quad' = quad ^ (row&7).
// ---------------------------------------------------------------------------
__global__ __launch_bounds__(256) void gemm_qkv(
    const u16* __restrict__ Ah, const u16* __restrict__ Bt,
    const float* __restrict__ bias,
    u16* __restrict__ Qb, u16* __restrict__ Kb, u16* __restrict__ Vb) {
  __shared__ __align__(16) u16 sA[64 * 64];    // 8 KB
  __shared__ __align__(16) u16 sB[128 * 64];   // 16 KB

  const int t = threadIdx.x, l = t & 63, w = t >> 6;
  const int wm = w >> 1, wn = w & 1;
  const int mBase = blockIdx.y * 64, nBase = blockIdx.x * 128;

  // staging: one glds = 8 rows x 8 quads. lane l -> row l>>3, LDS quad l&7,
  // global quad (l&7) ^ ((l>>3)&7).
  const int rsub = l >> 3;
  const int qsrc = (l & 7) ^ (rsub & 7);
  const u16* gA0 = Ah + (size_t)(mBase + w * 16 + rsub) * 512 + qsrc * 8;
  const u16* gA1 = Ah + (size_t)(mBase + w * 16 + 8 + rsub) * 512 + qsrc * 8;
  u16* lA0 = sA + (w * 16) * 64;
  u16* lA1 = sA + (w * 16 + 8) * 64;
  const u16* gB[4];
  u16* lB[4];
#pragma unroll
  for (int j = 0; j < 4; ++j) {
    gB[j] = Bt + (size_t)(nBase + w * 32 + j * 8 + rsub) * 512 + qsrc * 8;
    lB[j] = sB + (w * 32 + j * 8) * 64;
  }

  // fragment offsets: row*64 + ((s*4+kg) ^ (row&7))*8, s = k-step 0/1
  const int r15 = l & 15, kg = l >> 4;
  const int sw = r15 & 7;
  int aoff[2][2], boff[4][2];
#pragma unroll
  for (int mt = 0; mt < 2; ++mt)
#pragma unroll
    for (int s = 0; s < 2; ++s)
      aoff[mt][s] = (wm * 32 + mt * 16 + r15) * 64 + (((s * 4 + kg) ^ sw) * 8);
#pragma unroll
  for (int nt = 0; nt < 4; ++nt)
#pragma unroll
    for (int s = 0; s < 2; ++s)
      boff[nt][s] = (wn * 64 + nt * 16 + r15) * 64 + (((s * 4 + kg) ^ sw) * 8);

  f32x4 acc[2][4];
#pragma unroll
  for (int i = 0; i < 2; ++i)
#pragma unroll
    for (int j = 0; j < 4; ++j) acc[i][j] = (f32x4){0.f, 0.f, 0.f, 0.f};

  for (int k0 = 0; k0 < 512; k0 += 64) {
    glds16(gA0 + k0, lA0);
    glds16(gA1 + k0, lA1);
#pragma unroll
    for (int j = 0; j < 4; ++j) glds16(gB[j] + k0, lB[j]);
    __syncthreads();
#pragma unroll
    for (int s = 0; s < 2; ++s) {
      bf16x8 b[4];
#pragma unroll
      for (int nt = 0; nt < 4; ++nt) b[nt] = *(const bf16x8*)(sB + boff[nt][s]);
      bf16x8 a0 = *(const bf16x8*)(sA + aoff[0][s]);
      bf16x8 a1 = *(const bf16x8*)(sA + aoff[1][s]);
#pragma unroll
      for (int nt = 0; nt < 4; ++nt) {
        acc[0][nt] = mfma16(a0, b[nt], acc[0][nt]);
        acc[1][nt] = mfma16(a1, b[nt], acc[1][nt]);
      }
    }
    __syncthreads();
  }

  const int lq = l >> 4;
  const int seg = nBase >> 9, colb = nBase & 511;
#pragma unroll
  for (int mt = 0; mt < 2; ++mt) {
    int row0 = mBase + wm * 32 + mt * 16 + lq * 4;
#pragma unroll
    for (int nt = 0; nt < 4; ++nt) {
      int col = wn * 64 + nt * 16 + r15;
      float bv = bias[nBase + col];
      int cc = colb + col;
      if (seg == 0) {
#pragma unroll
        for (int r = 0; r < 4; ++r)
          Qb[(size_t)(row0 + r) * 512 + cc] = f2bf((acc[mt][nt][r] + bv) * 0.125f);
      } else if (seg == 1) {
#pragma unroll
        for (int r = 0; r < 4; ++r)
          Kb[(size_t)(row0 + r) * 512 + cc] = f2bf(acc[mt][nt][r] + bv);
      } else {
#pragma unroll
        for (int r = 0; r < 4; ++r)
          Vb[(size_t)(row0 + r) * 512 + cc] = f2bf(acc[mt][nt][r] + bv);
      }
    }
  }
}

// ---------------------------------------------------------------------------
// attn_mfma: per (64-row tile, h, b). QK^T and PV on matrix cores.
// Writes attention output as bf16 (single-product out-GEMM downstream).
// ---------------------------------------------------------------------------
__global__ __launch_bounds__(256) void attn_mfma(
    const u16* __restrict__ Qb, const u16* __restrict__ Kb,
    const u16* __restrict__ Vb, u16* __restrict__ Oh) {
  const int tile = blockIdx.x, h = blockIdx.y, b = blockIdx.z;
  const int base = tile * 64;
  const size_t hb = (size_t)b * 2048;

  __shared__ __align__(16) u16 Qs[64][72];    // [s][d]
  __shared__ __align__(16) u16 Ks[128][72];   // [j][d]
  __shared__ __align__(16) u16 Vt[64][136];   // [d][j]
  __shared__ __align__(16) u16 Pp[64][136];   // [s][j]

  const int t = threadIdx.x, l = t & 63, w = t >> 6;
  const int r15 = l & 15, kg = l >> 4;

  // stage Q
  {
    int r = t >> 2, c0 = (t & 3) * 16;
    const uint4* src = (const uint4*)&Qb[(hb + base + r) * 512 + h * 64 + c0];
    *(uint4*)&Qs[r][c0] = src[0];
    *(uint4*)&Qs[r][c0 + 8] = src[1];
  }
  // stage K (clamped band)
  {
    int j = t >> 1, half = (t & 1) * 32;
    int ja = min(max(base - 32 + j, 0), 2047);
    const uint4* src = (const uint4*)&Kb[(hb + ja) * 512 + h * 64 + half];
    uint4* dst = (uint4*)&Ks[j][half];
    dst[0] = src[0]; dst[1] = src[1]; dst[2] = src[2]; dst[3] = src[3];
  }
  // stage V transposed
  {
    int j = t >> 1, ds = (t & 1) * 32;
    int ja = min(max(base - 32 + j, 0), 2047);
    const u16* src = &Vb[(hb + ja) * 512 + h * 64 + ds];
    u16 tmp[32];
    *(uint4*)&tmp[0]  = *(const uint4*)(src);
    *(uint4*)&tmp[8]  = *(const uint4*)(src + 8);
    *(uint4*)&tmp[16] = *(const uint4*)(src + 16);
    *(uint4*)&tmp[24] = *(const uint4*)(src + 24);
#pragma unroll
    for (int i = 0; i < 32; ++i) Vt[ds + i][j] = tmp[i];
  }
  __syncthreads();

  // QK^T: wave w owns rows [w*16, w*16+16)
  bf16x8 aQ0 = *(const bf16x8*)&Qs[w * 16 + r15][kg * 8];
  bf16x8 aQ1 = *(const bf16x8*)&Qs[w * 16 + r15][32 + kg * 8];
  f32x4 zero = (f32x4){0.f, 0.f, 0.f, 0.f};
  f32x4 sacc[8];
#pragma unroll
  for (int nt = 0; nt < 8; ++nt) {
    bf16x8 b0 = *(const bf16x8*)&Ks[nt * 16 + r15][kg * 8];
    bf16x8 b1 = *(const bf16x8*)&Ks[nt * 16 + r15][32 + kg * 8];
    sacc[nt] = mfma16(aQ0, b0, zero);
    sacc[nt] = mfma16(aQ1, b1, sacc[nt]);
  }

  // mask + softmax (C-layout: row = w*16+kg*4+r, col = nt*16+r15)
#pragma unroll
  for (int r = 0; r < 4; ++r) {
    int s_abs = base + w * 16 + kg * 4 + r;
    float m = -3.0e38f;
#pragma unroll
    for (int nt = 0; nt < 8; ++nt) {
      int j_abs = base - 32 + nt * 16 + r15;
      int dlt = j_abs - s_abs;
      bool valid = (dlt >= -32) && (dlt <= 32) && (j_abs >= 0) && (j_abs < 2048);
      float v = valid ? sacc[nt][r] : -1.0e9f;
      sacc[nt][r] = v;
      m = fmaxf(m, v);
    }
#pragma unroll
    for (int msk = 1; msk < 16; msk <<= 1) m = fmaxf(m, __shfl_xor(m, msk, 64));
    float s_ = 0.f;
#pragma unroll
    for (int nt = 0; nt < 8; ++nt) {
      float e = __expf(sacc[nt][r] - m);
      sacc[nt][r] = e;
      s_ += e;
    }
#pragma unroll
    for (int msk = 1; msk < 16; msk <<= 1) s_ += __shfl_xor(s_, msk, 64);
    float inv = 1.0f / s_;
#pragma unroll
    for (int nt = 0; nt < 8; ++nt)
      Pp[w * 16 + kg * 4 + r][nt * 16 + r15] = f2bf(sacc[nt][r] * inv);
  }
  __syncthreads();

  // PV
  bf16x8 aP[4];
#pragma unroll
  for (int kt = 0; kt < 4; ++kt)
    aP[kt] = *(const bf16x8*)&Pp[w * 16 + r15][kt * 32 + kg * 8];
  f32x4 oacc[4];
#pragma unroll
  for (int nt = 0; nt < 4; ++nt) oacc[nt] = zero;
#pragma unroll
  for (int nt = 0; nt < 4; ++nt) {
#pragma unroll
    for (int kt = 0; kt < 4; ++kt) {
      bf16x8 bV = *(const bf16x8*)&Vt[nt * 16 + r15][kt * 32 + kg * 8];
      oacc[nt] = mfma16(aP[kt], bV, oacc[nt]);
    }
  }

  // epilogue: write O as bf16
#pragma unroll
  for (int nt = 0; nt < 4; ++nt) {
#pragma unroll
    for (int r = 0; r < 4; ++r) {
      size_t idx =
          (hb + base + w * 16 + kg * 4 + r) * 512 + h * 64 + nt * 16 + r15;
      Oh[idx] = f2bf(oacc[nt][r]);
    }
  }
}

// ---------------------------------------------------------------------------
// gemm_out: [4096,512](bf16) @ [512,512]^T(bf16) + bias -> fp32 out.
// Single-product. 64x128 tile, BK=64 (8 iters), 24 KB LDS, grid (4,64).
// ---------------------------------------------------------------------------
__global__ __launch_bounds__(256) void gemm_out(
    const u16* __restrict__ Ah, const u16* __restrict__ Bt,
    const float* __restrict__ bias, float* __restrict__ Cf) {
  __shared__ __align__(16) u16 sA[64 * 64];
  __shared__ __align__(16) u16 sB[128 * 64];

  const int t = threadIdx.x, l = t & 63, w = t >> 6;
  const int wm = w >> 1, wn = w & 1;
  const int mBase = blockIdx.y * 64, nBase = blockIdx.x * 128;

  const int rsub = l >> 3;
  const int qsrc = (l & 7) ^ (rsub & 7);
  const u16* gA0 = Ah + (size_t)(mBase + w * 16 + rsub) * 512 + qsrc * 8;
  const u16* gA1 = Ah + (size_t)(mBase + w * 16 + 8 + rsub) * 512 + qsrc * 8;
  u16* lA0 = sA + (w * 16) * 64;
  u16* lA1 = sA + (w * 16 + 8) * 64;
  const u16* gB[4];
  u16* lB[4];
#pragma unroll
  for (int j = 0; j < 4; ++j) {
    gB[j] = Bt + (size_t)(nBase + w * 32 + j * 8 + rsub) * 512 + qsrc * 8;
    lB[j] = sB + (w * 32 + j * 8) * 64;
  }

  const int r15 = l & 15, kg = l >> 4;
  const int sw = r15 & 7;
  int aoff[2][2], boff[4][2];
#pragma unroll
  for (int mt = 0; mt < 2; ++mt)
#pragma unroll
    for (int s = 0; s < 2; ++s)
      aoff[mt][s] = (wm * 32 + mt * 16 + r15) * 64 + (((s * 4 + kg) ^ sw) * 8);
#pragma unroll
  for (int nt = 0; nt < 4; ++nt)
#pragma unroll
    for (int s = 0; s < 2; ++s)
      boff[nt][s] = (wn * 64 + nt * 16 + r15) * 64 + (((s * 4 + kg) ^ sw) * 8);

  f32x4 acc[2][4];
#pragma unroll
  for (int i = 0; i < 2; ++i)
#pragma unroll
    for (int j = 0; j < 4; ++j) acc[i][j] = (f32x4){0.f, 0.f, 0.f, 0.f};

  for (int k0 = 0; k0 < 512; k0 += 64) {
    glds16(gA0 + k0, lA0);
    glds16(gA1 + k0, lA1);
#pragma unroll
    for (int j = 0; j < 4; ++j) glds16(gB[j] + k0, lB[j]);
    __syncthreads();
#pragma unroll
    for (int s = 0; s < 2; ++s) {
      bf16x8 b[4];
#pragma unroll
      for (int nt = 0; nt < 4; ++nt) b[nt] = *(const bf16x8*)(sB + boff[nt][s]);
      bf16x8 a0 = *(const bf16x8*)(sA + aoff[0][s]);
      bf16x8 a1 = *(const bf16x8*)(sA + aoff[1][s]);
#pragma unroll
      for (int nt = 0; nt < 4; ++nt) {
        acc[0][nt] = mfma16(a0, b[nt], acc[0][nt]);
        acc[1][nt] = mfma16(a1, b[nt], acc[1][nt]);
      }
    }
    __syncthreads();
  }

  const int lq = l >> 4;
#pragma unroll
  for (int mt = 0; mt < 2; ++mt) {
    int row0 = mBase + wm * 32 + mt * 16 + lq * 4;
#pragma unroll
    for (int nt = 0; nt < 4; ++nt) {
      int col = nBase + wn * 64 + nt * 16 + r15;
      float bv = bias[col];
#pragma unroll
      for (int r = 0; r < 4; ++r)
        Cf[(size_t)(row0 + r) * 512 + col] = acc[mt][nt][r] + bv;
    }
  }
}

// ---------------------------------------------------------------------------
extern "C" void kernel_launch(void* const* d_in, const int* in_sizes, int n_in,
                              void* d_out, int out_size, void* d_ws, size_t ws_size,
                              hipStream_t stream) {
  const float* x     = (const float*)d_in[0];
  const float* w_qkv = (const float*)d_in[1];
  const float* b_qkv = (const float*)d_in[2];
  const float* w_out = (const float*)d_in[3];
  const float* b_out = (const float*)d_in[4];
  float* out = (float*)d_out;

  // workspace layout (~22.6 MB)
  char* ws = (char*)d_ws;
  u16* xh  = (u16*)(ws + 0);          // 4096x512 bf16 = 4194304
  u16* wqt = (u16*)(ws + 4194304);    // 1536x512 bf16 = 1572864
  u16* wot = (u16*)(ws + 5767168);    // 512x512 bf16  = 524288
  u16* qb  = (u16*)(ws + 6291456);    // 4096x512 bf16 (pre-scaled) = 4194304
  u16* kb  = (u16*)(ws + 10485760);   // 4194304
  u16* vb  = (u16*)(ws + 14680064);   // 4194304
  u16* aoh = (u16*)(ws + 18874368);   // 4194304

  prep<<<3072, 256, 0, stream>>>((const float4*)x, (uint2*)xh,
                                 w_qkv, wqt, w_out, wot);
  gemm_qkv<<<dim3(12, 64), 256, 0, stream>>>(xh, wqt, b_qkv, qb, kb, vb);
  attn_mfma<<<dim3(32, 8, 2), 256, 0, stream>>>(qb, kb, vb, aoh);
  gemm_out<<<dim3(4, 64), 256, 0, stream>>>(aoh, wot, b_out, out);
}